// Round 1
// baseline (6998.307 us; speedup 1.0000x reference)
//
#include <hip/hip_runtime.h>
#include <hip/hip_bf16.h>
#include <cstdint>
#include <cstddef>

#define N_K   1024
#define N_E   20480
#define NB    (N_K + N_E)
#define D_IN  4096
#define D_OUT 1024
#define EK_   65536
#define EB_   131072

// ---------------------------------------------------------------- zero fills
__global__ void zero_f32(float* p, size_t n) {
  size_t i = (size_t)blockIdx.x * blockDim.x + threadIdx.x;
  size_t st = (size_t)gridDim.x * blockDim.x;
  for (; i < n; i += st) p[i] = 0.f;
}
__global__ void zero_i32(int* p, int n) {
  int i = blockIdx.x * blockDim.x + threadIdx.x;
  int st = gridDim.x * blockDim.x;
  for (; i < n; i += st) p[i] = 0;
}

// ---------------------------------------------------------------- GEMM: Z = H @ W^T
// H rows: r < split -> Ha[r], else Hb[r-split]  (handles concat([exer, kn]))
// 128x128 tile, BK=32, 256 threads, 8x8 per thread, fp32.
#define TM 128
#define TN 128
#define TK 32
#define LDS_A (TM + 4)
#define LDS_B (TN + 4)

__global__ __launch_bounds__(256)
void gemm_nt(const float* __restrict__ Ha, const float* __restrict__ Hb, int split,
             const float* __restrict__ W, float* __restrict__ Z, int M) {
  __shared__ float As[TK][LDS_A];
  __shared__ float Bs[TK][LDS_B];
  const int tid  = threadIdx.x;
  const int bm   = blockIdx.y * TM;
  const int bn   = blockIdx.x * TN;
  const int trow = (tid >> 4) * 8;   // 0..120
  const int tcol = (tid & 15) * 8;   // 0..120
  float acc[8][8] = {};

  for (int k0 = 0; k0 < D_IN; k0 += TK) {
#pragma unroll
    for (int i = 0; i < 4; ++i) {
      int idx = tid + i * 256;       // 0..1023
      int row = idx >> 3;            // 0..127
      int kq  = (idx & 7) * 4;       // 0..28
      int gr  = bm + row;
      const float* srcp = (gr < split) ? (Ha + (size_t)gr * D_IN + k0 + kq)
                                       : (Hb + (size_t)(gr - split) * D_IN + k0 + kq);
      float4 va = *reinterpret_cast<const float4*>(srcp);
      As[kq + 0][row] = va.x; As[kq + 1][row] = va.y;
      As[kq + 2][row] = va.z; As[kq + 3][row] = va.w;
      float4 vb = *reinterpret_cast<const float4*>(W + (size_t)(bn + row) * D_IN + k0 + kq);
      Bs[kq + 0][row] = vb.x; Bs[kq + 1][row] = vb.y;
      Bs[kq + 2][row] = vb.z; Bs[kq + 3][row] = vb.w;
    }
    __syncthreads();
#pragma unroll
    for (int kk = 0; kk < TK; ++kk) {
      float a[8], b[8];
#pragma unroll
      for (int j = 0; j < 8; ++j) a[j] = As[kk][trow + j];
#pragma unroll
      for (int j = 0; j < 8; ++j) b[j] = Bs[kk][tcol + j];
#pragma unroll
      for (int x = 0; x < 8; ++x)
#pragma unroll
        for (int y = 0; y < 8; ++y)
          acc[x][y] = fmaf(a[x], b[y], acc[x][y]);
    }
    __syncthreads();
  }
#pragma unroll
  for (int x = 0; x < 8; ++x) {
    float4 v0 = make_float4(acc[x][0], acc[x][1], acc[x][2], acc[x][3]);
    float4 v1 = make_float4(acc[x][4], acc[x][5], acc[x][6], acc[x][7]);
    float* zp = Z + (size_t)(bm + trow + x) * D_OUT + (bn + tcol);
    *reinterpret_cast<float4*>(zp)     = v0;
    *reinterpret_cast<float4*>(zp + 4) = v1;
  }
}

// ---------------------------------------------------------------- s_src = Z @ a[:D_OUT]
// (s_dst is provably irrelevant: softmax over a segment is shift-invariant,
//  and s_dst[dst] is constant within a dst-segment.)
__global__ __launch_bounds__(256)
void row_dot(const float* __restrict__ Z, const float* __restrict__ a,
             float* __restrict__ s) {
  const int row = blockIdx.x;
  const int t   = threadIdx.x;
  float4 z4 = *reinterpret_cast<const float4*>(Z + (size_t)row * D_OUT + t * 4);
  float4 a4 = *reinterpret_cast<const float4*>(a + t * 4);
  float sum = z4.x * a4.x + z4.y * a4.y + z4.z * a4.z + z4.w * a4.w;
#pragma unroll
  for (int off = 32; off; off >>= 1) sum += __shfl_down(sum, off);
  __shared__ float red_s[4];
  if ((t & 63) == 0) red_s[t >> 6] = sum;
  __syncthreads();
  if (t == 0) s[row] = red_s[0] + red_s[1] + red_s[2] + red_s[3];
}

// ---------------------------------------------------------------- CSR build
__global__ void hist_k(const int* __restrict__ dst, int* __restrict__ deg, int E) {
  for (int e = blockIdx.x * blockDim.x + threadIdx.x; e < E; e += gridDim.x * blockDim.x)
    atomicAdd(&deg[dst[e]], 1);
}

// single-block exclusive scan over n (<= NB) elements; also writes offs[n]=total
__global__ __launch_bounds__(1024)
void scan_excl(const int* __restrict__ deg, int* __restrict__ offs,
               int* __restrict__ cursor, int n) {
  __shared__ int warpsums[16];
  __shared__ int carry_s;
  const int t = threadIdx.x;
  if (t == 0) carry_s = 0;
  __syncthreads();
  for (int base = 0; base < n; base += 1024) {
    int i = base + t;
    int v = (i < n) ? deg[i] : 0;
    int x = v;
#pragma unroll
    for (int off = 1; off < 64; off <<= 1) {
      int y = __shfl_up(x, off);
      if ((t & 63) >= off) x += y;
    }
    if ((t & 63) == 63) warpsums[t >> 6] = x;
    __syncthreads();
    if (t < 16) {
      int ws = warpsums[t];
#pragma unroll
      for (int off = 1; off < 16; off <<= 1) {
        int y = __shfl_up(ws, off);
        if (t >= off) ws += y;
      }
      warpsums[t] = ws;
    }
    __syncthreads();
    int waveoff = (t >> 6) ? warpsums[(t >> 6) - 1] : 0;
    int incl = x + waveoff + carry_s;
    int excl = incl - v;
    if (i < n) { offs[i] = excl; cursor[i] = excl; }
    __syncthreads();
    if (t == 1023) carry_s = incl;
    __syncthreads();
  }
  if (t == 0) offs[n] = carry_s;
}

__global__ void scatter_k(const int* __restrict__ src, const int* __restrict__ dst,
                          int* __restrict__ cursor, int* __restrict__ csr, int E) {
  for (int e = blockIdx.x * blockDim.x + threadIdx.x; e < E; e += gridDim.x * blockDim.x) {
    int pos = atomicAdd(&cursor[dst[e]], 1);
    csr[pos] = src[e];
  }
}

// ---------------------------------------------------------------- segment softmax + aggregate
// One block per OUTPUT row. node = node_base + blockIdx.x. out row = blockIdx.x.
// out is accumulated (+=) -- d_out zero-initialized, GATs run sequentially.
__global__ __launch_bounds__(256)
void gat_agg(const float* __restrict__ Z, const float* __restrict__ s,
             const int* __restrict__ offs, const int* __restrict__ csr,
             float* __restrict__ outp, int node_base) {
  const int t     = threadIdx.x;
  const int node  = node_base + blockIdx.x;
  const int start = offs[node];
  const int deg   = offs[node + 1] - start;
  if (deg == 0) return;  // empty segment -> output row stays 0 (matches reference)

  __shared__ float wbuf[256];
  __shared__ int   sbuf[256];
  __shared__ float red_s[4];

  // pass 1: segment max of s[src]
  float mx = -INFINITY;
  for (int j = t; j < deg; j += 256) mx = fmaxf(mx, s[csr[start + j]]);
#pragma unroll
  for (int off = 32; off; off >>= 1) mx = fmaxf(mx, __shfl_down(mx, off));
  if ((t & 63) == 0) red_s[t >> 6] = mx;
  __syncthreads();
  mx = fmaxf(fmaxf(red_s[0], red_s[1]), fmaxf(red_s[2], red_s[3]));
  __syncthreads();

  // pass 2: denom
  float dsum = 0.f;
  for (int j = t; j < deg; j += 256) dsum += expf(s[csr[start + j]] - mx);
#pragma unroll
  for (int off = 32; off; off >>= 1) dsum += __shfl_down(dsum, off);
  if ((t & 63) == 0) red_s[t >> 6] = dsum;
  __syncthreads();
  const float inv = 1.f / (red_s[0] + red_s[1] + red_s[2] + red_s[3]);

  // pass 3: out[row] += sum_j alpha_j * Z[src_j]
  float4 acc = make_float4(0.f, 0.f, 0.f, 0.f);
  for (int c0 = 0; c0 < deg; c0 += 256) {
    int cn = min(256, deg - c0);
    __syncthreads();
    if (t < cn) {
      int sv = csr[start + c0 + t];
      sbuf[t] = sv;
      wbuf[t] = expf(s[sv] - mx) * inv;
    }
    __syncthreads();
    for (int j = 0; j < cn; ++j) {
      float w = wbuf[j];
      float4 z4 = *reinterpret_cast<const float4*>(Z + (size_t)sbuf[j] * D_OUT + t * 4);
      acc.x = fmaf(w, z4.x, acc.x);
      acc.y = fmaf(w, z4.y, acc.y);
      acc.z = fmaf(w, z4.z, acc.z);
      acc.w = fmaf(w, z4.w, acc.w);
    }
  }
  float* orow = outp + (size_t)blockIdx.x * D_OUT + t * 4;
  float4 cur = *reinterpret_cast<float4*>(orow);
  cur.x += acc.x; cur.y += acc.y; cur.z += acc.z; cur.w += acc.w;
  *reinterpret_cast<float4*>(orow) = cur;
}

// ---------------------------------------------------------------- launch
extern "C" void kernel_launch(void* const* d_in, const int* in_sizes, int n_in,
                              void* d_out, int out_size, void* d_ws, size_t ws_size,
                              hipStream_t stream) {
  const float* kn      = (const float*)d_in[0];
  const float* exer    = (const float*)d_in[1];
  const int*   dir_src = (const int*)d_in[2];
  const int*   dir_dst = (const int*)d_in[3];
  const int*   und_src = (const int*)d_in[4];
  const int*   und_dst = (const int*)d_in[5];
  const int*   kfe_src = (const int*)d_in[6];
  const int*   kfe_dst = (const int*)d_in[7];
  const int*   efk_src = (const int*)d_in[8];
  const int*   efk_dst = (const int*)d_in[9];
  const float* W_dir   = (const float*)d_in[10];
  const float* a_dir   = (const float*)d_in[11];
  const float* W_und   = (const float*)d_in[12];
  const float* a_und   = (const float*)d_in[13];
  const float* W_kfe   = (const float*)d_in[14];
  const float* a_kfe   = (const float*)d_in[15];
  const float* W_efk   = (const float*)d_in[16];
  const float* a_efk   = (const float*)d_in[17];
  float* out = (float*)d_out;

  // workspace carve-up (Z reused across the 4 sequential GATs): ~89 MB
  char* wsp = (char*)d_ws;
  float* Z      = (float*)wsp;  wsp += (size_t)NB * D_OUT * sizeof(float);
  float* s      = (float*)wsp;  wsp += (size_t)NB * sizeof(float);
  int*   deg    = (int*)wsp;    wsp += (size_t)NB * sizeof(int);
  int*   offs   = (int*)wsp;    wsp += (size_t)(NB + 1) * sizeof(int);
  int*   cursor = (int*)wsp;    wsp += (size_t)NB * sizeof(int);
  int*   csr    = (int*)wsp;    wsp += (size_t)EB_ * sizeof(int);

  zero_f32<<<2048, 256, 0, stream>>>(out, (size_t)NB * D_OUT);

  struct Cfg {
    const float* Ha; const float* Hb; int split; int M;
    const float* W; const float* a;
    const int* esrc; const int* edst; int E; int n;
    float* outp; int node_base; int out_rows;
  };
  const Cfg cfgs[4] = {
    { kn,   kn, N_K, N_K, W_dir, a_dir, dir_src, dir_dst, EK_, N_K, out,                       0,   N_K },
    { kn,   kn, N_K, N_K, W_und, a_und, und_src, und_dst, EK_, N_K, out,                       0,   N_K },
    { exer, kn, N_E, NB,  W_kfe, a_kfe, kfe_src, kfe_dst, EB_, NB,  out,                       N_E, N_K },
    { exer, kn, N_E, NB,  W_efk, a_efk, efk_src, efk_dst, EB_, NB,  out + (size_t)N_K * D_OUT, 0,   N_E },
  };

  for (int g = 0; g < 4; ++g) {
    const Cfg& c = cfgs[g];
    dim3 gg(D_OUT / TN, c.M / TM);
    gemm_nt<<<gg, 256, 0, stream>>>(c.Ha, c.Hb, c.split, c.W, Z, c.M);
    row_dot<<<c.M, 256, 0, stream>>>(Z, c.a, s);
    zero_i32<<<64, 256, 0, stream>>>(deg, c.n);
    hist_k<<<256, 256, 0, stream>>>(c.edst, deg, c.E);
    scan_excl<<<1, 1024, 0, stream>>>(deg, offs, cursor, c.n);
    scatter_k<<<256, 256, 0, stream>>>(c.esrc, c.edst, cursor, csr, c.E);
    gat_agg<<<c.out_rows, 256, 0, stream>>>(Z, s, offs, csr, c.outp, c.node_base);
  }
}

// Round 2
// 3504.374 us; speedup vs baseline: 1.9970x; 1.9970x over previous
//
#include <hip/hip_runtime.h>
#include <hip/hip_bf16.h>
#include <cstdint>
#include <cstddef>

#define N_K   1024
#define N_E   20480
#define NB    (N_K + N_E)
#define D_IN  4096
#define D_OUT 1024
#define EK_   65536
#define EB_   131072

typedef __attribute__((ext_vector_type(8))) short short8;   // 8 bf16 = 4 VGPRs
typedef __attribute__((ext_vector_type(4))) float f32x4;

// ---------------------------------------------------------------- zero fills
__global__ void zero_f32(float* p, size_t n) {
  size_t i = (size_t)blockIdx.x * blockDim.x + threadIdx.x;
  size_t st = (size_t)gridDim.x * blockDim.x;
  for (; i < n; i += st) p[i] = 0.f;
}
__global__ void zero_i32(int* p, int n) {
  int i = blockIdx.x * blockDim.x + threadIdx.x;
  int st = gridDim.x * blockDim.x;
  for (; i < n; i += st) p[i] = 0;
}

// ---------------------------------------------------------------- fp32 -> (hi,lo) bf16 split
// hi = truncate-to-bf16 (exact high 16 bits), lo = bf16(x - hi) (truncated).
// (hi+lo) recovers ~16 mantissa bits; dropped lo*lo term ~2^-16 relative.
__device__ inline void cvt_split4(float4 v, uint2& hi, uint2& lo) {
  uint32_t ux = __float_as_uint(v.x), uy = __float_as_uint(v.y),
           uz = __float_as_uint(v.z), uw = __float_as_uint(v.w);
  uint32_t hx = ux & 0xFFFF0000u, hy = uy & 0xFFFF0000u,
           hz = uz & 0xFFFF0000u, hw = uw & 0xFFFF0000u;
  hi.x = (hx >> 16) | hy;
  hi.y = (hz >> 16) | hw;
  float lx = v.x - __uint_as_float(hx);
  float ly = v.y - __uint_as_float(hy);
  float lz = v.z - __uint_as_float(hz);
  float lw = v.w - __uint_as_float(hw);
  lo.x = (__float_as_uint(lx) >> 16) | (__float_as_uint(ly) & 0xFFFF0000u);
  lo.y = (__float_as_uint(lz) >> 16) | (__float_as_uint(lw) & 0xFFFF0000u);
}

// ---------------------------------------------------------------- split-bf16 MFMA GEMM
// Z = H @ W^T  (+ fused s = Z @ avec, via atomicAdd)
// H rows: r < split -> Ha[r], else Hb[r-split].
// 128x128 tile, BK=32, 256 threads (4 waves, 2x2), 16x16x32 bf16 MFMA,
// 3 MFMAs per fragment pair (hi*hi + hi*lo + lo*hi).
#define LDK 40   // padded LDS row stride in bf16 elems (80 B) -> 2-way banks (free)

__global__ __launch_bounds__(256, 2)
void gemm_split3(const float* __restrict__ Ha, const float* __restrict__ Hb, int split,
                 const float* __restrict__ W, const float* __restrict__ avec,
                 float* __restrict__ Z, float* __restrict__ s_out, int M) {
  __shared__ ushort sAh[128 * LDK];
  __shared__ ushort sAl[128 * LDK];
  __shared__ ushort sBh[128 * LDK];
  __shared__ ushort sBl[128 * LDK];

  const int tid  = threadIdx.x;
  const int lane = tid & 63;
  const int wave = tid >> 6;
  const int wm = wave >> 1, wn = wave & 1;
  const int l15 = lane & 15;
  const int l4  = lane >> 4;

  // XCD-aware bijective swizzle: all 8 column-blocks of a row-panel -> same XCD
  // (nY % 8 == 0 holds: 168 and 8). dispatch assumption f%8->XCD is perf-only.
  const int nY = M >> 7;
  const int chunk = nY >> 3;
  int f = blockIdx.x;
  int xcd = f & 7;
  int i0  = f >> 3;
  int y = xcd * chunk + (i0 >> 3);
  int x = i0 & 7;
  const int bm = y * 128, bn = x * 128;

  // staging: thread owns float4 p = tid + j*256 (j=0..3): row=p>>3, f4slot=p&7
  const int srow = tid >> 3;   // +32 per j
  const int sf4  = tid & 7;

  f32x4 acc[4][4];
#pragma unroll
  for (int i = 0; i < 4; ++i)
#pragma unroll
    for (int j = 0; j < 4; ++j) acc[i][j] = (f32x4){0.f, 0.f, 0.f, 0.f};

  for (int k0 = 0; k0 < D_IN; k0 += 32) {
    // issue global loads early (overlap previous MFMA phase)
    float4 va[4], vb[4];
#pragma unroll
    for (int j = 0; j < 4; ++j) {
      int row = srow + j * 32;
      int gr = bm + row;
      const float* ap = (gr < split) ? Ha + (size_t)gr * D_IN
                                     : Hb + (size_t)(gr - split) * D_IN;
      va[j] = *reinterpret_cast<const float4*>(ap + k0 + sf4 * 4);
      vb[j] = *reinterpret_cast<const float4*>(W + (size_t)(bn + row) * D_IN + k0 + sf4 * 4);
    }
    __syncthreads();  // previous iteration's fragment reads complete
#pragma unroll
    for (int j = 0; j < 4; ++j) {
      int row = srow + j * 32;
      uint2 h, l;
      cvt_split4(va[j], h, l);
      *reinterpret_cast<uint2*>(&sAh[row * LDK + sf4 * 4]) = h;
      *reinterpret_cast<uint2*>(&sAl[row * LDK + sf4 * 4]) = l;
      cvt_split4(vb[j], h, l);
      *reinterpret_cast<uint2*>(&sBh[row * LDK + sf4 * 4]) = h;
      *reinterpret_cast<uint2*>(&sBl[row * LDK + sf4 * 4]) = l;
    }
    __syncthreads();

    short8 ah[4], al[4], bh[4], bl[4];
#pragma unroll
    for (int i = 0; i < 4; ++i) {
      int row = wm * 64 + i * 16 + l15;
      ah[i] = *reinterpret_cast<const short8*>(&sAh[row * LDK + l4 * 8]);
      al[i] = *reinterpret_cast<const short8*>(&sAl[row * LDK + l4 * 8]);
    }
#pragma unroll
    for (int j = 0; j < 4; ++j) {
      int row = wn * 64 + j * 16 + l15;
      bh[j] = *reinterpret_cast<const short8*>(&sBh[row * LDK + l4 * 8]);
      bl[j] = *reinterpret_cast<const short8*>(&sBl[row * LDK + l4 * 8]);
    }
#pragma unroll
    for (int i = 0; i < 4; ++i)
#pragma unroll
      for (int j = 0; j < 4; ++j) {
        acc[i][j] = __builtin_amdgcn_mfma_f32_16x16x32_bf16(ah[i], bh[j], acc[i][j], 0, 0, 0);
        acc[i][j] = __builtin_amdgcn_mfma_f32_16x16x32_bf16(ah[i], bl[j], acc[i][j], 0, 0, 0);
        acc[i][j] = __builtin_amdgcn_mfma_f32_16x16x32_bf16(al[i], bh[j], acc[i][j], 0, 0, 0);
      }
  }

  // epilogue: store Z and fused s = Z @ avec (C/D layout: col=lane&15, row=(lane>>4)*4+q)
  float av[4];
#pragma unroll
  for (int j = 0; j < 4; ++j) av[j] = avec[bn + wn * 64 + j * 16 + l15];

#pragma unroll
  for (int i = 0; i < 4; ++i) {
    int rbase = bm + wm * 64 + i * 16 + l4 * 4;
#pragma unroll
    for (int q = 0; q < 4; ++q) {
      int gr = rbase + q;
      float dot = 0.f;
#pragma unroll
      for (int j = 0; j < 4; ++j) {
        float v = acc[i][j][q];
        Z[(size_t)gr * D_OUT + bn + wn * 64 + j * 16 + l15] = v;
        dot = fmaf(v, av[j], dot);
      }
      dot += __shfl_xor(dot, 1);
      dot += __shfl_xor(dot, 2);
      dot += __shfl_xor(dot, 4);
      dot += __shfl_xor(dot, 8);
      if (l15 == 0) atomicAdd(&s_out[gr], dot);
    }
  }
}

// ---------------------------------------------------------------- CSR build
__global__ void hist_k(const int* __restrict__ dst, int* __restrict__ deg, int E) {
  for (int e = blockIdx.x * blockDim.x + threadIdx.x; e < E; e += gridDim.x * blockDim.x)
    atomicAdd(&deg[dst[e]], 1);
}

__global__ __launch_bounds__(1024)
void scan_excl(const int* __restrict__ deg, int* __restrict__ offs,
               int* __restrict__ cursor, int n) {
  __shared__ int warpsums[16];
  __shared__ int carry_s;
  const int t = threadIdx.x;
  if (t == 0) carry_s = 0;
  __syncthreads();
  for (int base = 0; base < n; base += 1024) {
    int i = base + t;
    int v = (i < n) ? deg[i] : 0;
    int x = v;
#pragma unroll
    for (int off = 1; off < 64; off <<= 1) {
      int y = __shfl_up(x, off);
      if ((t & 63) >= off) x += y;
    }
    if ((t & 63) == 63) warpsums[t >> 6] = x;
    __syncthreads();
    if (t < 16) {
      int ws = warpsums[t];
#pragma unroll
      for (int off = 1; off < 16; off <<= 1) {
        int y = __shfl_up(ws, off);
        if (t >= off) ws += y;
      }
      warpsums[t] = ws;
    }
    __syncthreads();
    int waveoff = (t >> 6) ? warpsums[(t >> 6) - 1] : 0;
    int incl = x + waveoff + carry_s;
    int excl = incl - v;
    if (i < n) { offs[i] = excl; cursor[i] = excl; }
    __syncthreads();
    if (t == 1023) carry_s = incl;
    __syncthreads();
  }
  if (t == 0) offs[n] = carry_s;
}

__global__ void scatter_k(const int* __restrict__ src, const int* __restrict__ dst,
                          int* __restrict__ cursor, int* __restrict__ csr, int E) {
  for (int e = blockIdx.x * blockDim.x + threadIdx.x; e < E; e += gridDim.x * blockDim.x) {
    int pos = atomicAdd(&cursor[dst[e]], 1);
    csr[pos] = src[e];
  }
}

// ---------------------------------------------------------------- segment softmax + aggregate
__global__ __launch_bounds__(256)
void gat_agg(const float* __restrict__ Z, const float* __restrict__ s,
             const int* __restrict__ offs, const int* __restrict__ csr,
             float* __restrict__ outp, int node_base) {
  const int t     = threadIdx.x;
  const int node  = node_base + blockIdx.x;
  const int start = offs[node];
  const int deg   = offs[node + 1] - start;
  if (deg == 0) return;

  __shared__ float wbuf[256];
  __shared__ int   sbuf[256];
  __shared__ float red_s[4];

  float mx = -INFINITY;
  for (int j = t; j < deg; j += 256) mx = fmaxf(mx, s[csr[start + j]]);
#pragma unroll
  for (int off = 32; off; off >>= 1) mx = fmaxf(mx, __shfl_down(mx, off));
  if ((t & 63) == 0) red_s[t >> 6] = mx;
  __syncthreads();
  mx = fmaxf(fmaxf(red_s[0], red_s[1]), fmaxf(red_s[2], red_s[3]));
  __syncthreads();

  float dsum = 0.f;
  for (int j = t; j < deg; j += 256) dsum += expf(s[csr[start + j]] - mx);
#pragma unroll
  for (int off = 32; off; off >>= 1) dsum += __shfl_down(dsum, off);
  if ((t & 63) == 0) red_s[t >> 6] = dsum;
  __syncthreads();
  const float inv = 1.f / (red_s[0] + red_s[1] + red_s[2] + red_s[3]);

  float4 acc = make_float4(0.f, 0.f, 0.f, 0.f);
  for (int c0 = 0; c0 < deg; c0 += 256) {
    int cn = min(256, deg - c0);
    __syncthreads();
    if (t < cn) {
      int sv = csr[start + c0 + t];
      sbuf[t] = sv;
      wbuf[t] = expf(s[sv] - mx) * inv;
    }
    __syncthreads();
    for (int j = 0; j < cn; ++j) {
      float w = wbuf[j];
      float4 z4 = *reinterpret_cast<const float4*>(Z + (size_t)sbuf[j] * D_OUT + t * 4);
      acc.x = fmaf(w, z4.x, acc.x);
      acc.y = fmaf(w, z4.y, acc.y);
      acc.z = fmaf(w, z4.z, acc.z);
      acc.w = fmaf(w, z4.w, acc.w);
    }
  }
  float* orow = outp + (size_t)blockIdx.x * D_OUT + t * 4;
  float4 cur = *reinterpret_cast<float4*>(orow);
  cur.x += acc.x; cur.y += acc.y; cur.z += acc.z; cur.w += acc.w;
  *reinterpret_cast<float4*>(orow) = cur;
}

// ---------------------------------------------------------------- launch
extern "C" void kernel_launch(void* const* d_in, const int* in_sizes, int n_in,
                              void* d_out, int out_size, void* d_ws, size_t ws_size,
                              hipStream_t stream) {
  const float* kn      = (const float*)d_in[0];
  const float* exer    = (const float*)d_in[1];
  const int*   dir_src = (const int*)d_in[2];
  const int*   dir_dst = (const int*)d_in[3];
  const int*   und_src = (const int*)d_in[4];
  const int*   und_dst = (const int*)d_in[5];
  const int*   kfe_src = (const int*)d_in[6];
  const int*   kfe_dst = (const int*)d_in[7];
  const int*   efk_src = (const int*)d_in[8];
  const int*   efk_dst = (const int*)d_in[9];
  const float* W_dir   = (const float*)d_in[10];
  const float* a_dir   = (const float*)d_in[11];
  const float* W_und   = (const float*)d_in[12];
  const float* a_und   = (const float*)d_in[13];
  const float* W_kfe   = (const float*)d_in[14];
  const float* a_kfe   = (const float*)d_in[15];
  const float* W_efk   = (const float*)d_in[16];
  const float* a_efk   = (const float*)d_in[17];
  float* out = (float*)d_out;

  char* wsp = (char*)d_ws;
  float* Z      = (float*)wsp;  wsp += (size_t)NB * D_OUT * sizeof(float);
  float* s      = (float*)wsp;  wsp += (size_t)NB * sizeof(float);
  int*   deg    = (int*)wsp;    wsp += (size_t)NB * sizeof(int);
  int*   offs   = (int*)wsp;    wsp += (size_t)(NB + 1) * sizeof(int);
  int*   cursor = (int*)wsp;    wsp += (size_t)NB * sizeof(int);
  int*   csr    = (int*)wsp;    wsp += (size_t)EB_ * sizeof(int);

  zero_f32<<<2048, 256, 0, stream>>>(out, (size_t)NB * D_OUT);

  struct Cfg {
    const float* Ha; const float* Hb; int split; int M;
    const float* W; const float* a;
    const int* esrc; const int* edst; int E; int n;
    float* outp; int node_base; int out_rows;
  };
  const Cfg cfgs[4] = {
    { kn,   kn, N_K, N_K, W_dir, a_dir, dir_src, dir_dst, EK_, N_K, out,                       0,   N_K },
    { kn,   kn, N_K, N_K, W_und, a_und, und_src, und_dst, EK_, N_K, out,                       0,   N_K },
    { exer, kn, N_E, NB,  W_kfe, a_kfe, kfe_src, kfe_dst, EB_, NB,  out,                       N_E, N_K },
    { exer, kn, N_E, NB,  W_efk, a_efk, efk_src, efk_dst, EB_, NB,  out + (size_t)N_K * D_OUT, 0,   N_E },
  };

  for (int g = 0; g < 4; ++g) {
    const Cfg& c = cfgs[g];
    zero_f32<<<64, 256, 0, stream>>>(s, (size_t)c.M);
    int nblk = (c.M >> 7) * (D_OUT / 128);
    gemm_split3<<<nblk, 256, 0, stream>>>(c.Ha, c.Hb, c.split, c.W, c.a, Z, s, c.M);
    zero_i32<<<64, 256, 0, stream>>>(deg, c.n);
    hist_k<<<256, 256, 0, stream>>>(c.edst, deg, c.E);
    scan_excl<<<1, 1024, 0, stream>>>(deg, offs, cursor, c.n);
    scatter_k<<<256, 256, 0, stream>>>(c.esrc, c.edst, cursor, csr, c.E);
    gat_agg<<<c.out_rows, 256, 0, stream>>>(Z, s, offs, csr, c.outp, c.node_base);
  }
}